// Round 13
// baseline (277.866 us; speedup 1.0000x reference)
//
#include <hip/hip_runtime.h>
#include <stdint.h>

#define B_   256
#define NPG  512
#define NG   131072
#define EPG  4096
#define NQPG 16
#define NQ   4096
#define EQPG 128
#define L_   2
#define HPITCH 136   // LDS row pitch in shorts (272 B)

typedef __attribute__((ext_vector_type(8))) short short8;
typedef __attribute__((ext_vector_type(4))) float floatx4;
typedef __attribute__((ext_vector_type(2))) float float2v;

__device__ inline float bf2f(unsigned short u){
    union { unsigned int i; float f; } x; x.i = ((unsigned int)u) << 16; return x.f;
}
__device__ inline unsigned short f2bf(float f){
    union { float f; unsigned int i; } x; x.f = f;
    unsigned int r = x.i + 0x7fff + ((x.i >> 16) & 1);  // RNE
    return (unsigned short)(r >> 16);
}
// unpack u32 (2×bf16) -> float2v {lo, hi}
__device__ inline float2v bf2x2(unsigned int u){
    union { unsigned int i; float f; } lo, hi;
    lo.i = u << 16; hi.i = u & 0xffff0000u;
    float2v r; r.x = lo.f; r.y = hi.f; return r;
}
__device__ inline float d2(unsigned int a, unsigned int b, float c){
#if __has_builtin(__builtin_amdgcn_fdot2_f32_bf16)
    typedef __attribute__((ext_vector_type(2))) __bf16 bf16x2;
    union { unsigned int u; bf16x2 v; } xa, xb;
    xa.u = a; xb.u = b;
    return __builtin_amdgcn_fdot2_f32_bf16(xa.v, xb.v, c, false);
#else
    union { unsigned int u; float f; } la, ha, lb, hb;
    la.u = a << 16; ha.u = a & 0xffff0000u;
    lb.u = b << 16; hb.u = b & 0xffff0000u;
    return fmaf(la.f, lb.f, fmaf(ha.f, hb.f, c));
#endif
}
__device__ inline float dot8(uint4 a, uint4 b){
    return d2(a.x,b.x, d2(a.y,b.y, d2(a.z,b.z, d2(a.w,b.w, 0.f))));
}
__device__ inline float dot8q(uint4 a, uint4 b, float c0){
    return d2(a.x,b.x, d2(a.y,b.y, d2(a.z,b.z, d2(a.w,b.w, c0))));
}

#if __has_builtin(__builtin_amdgcn_exp2f)
#define FEXP2(x) __builtin_amdgcn_exp2f(x)
#else
#define FEXP2(x) __expf((x) * 0.6931471805599453f)
#endif
#define LOG2E_ 1.4426950408889634f

// 16-lane all-reduce sum via DPP (VALU pipe).
__device__ inline float red16dpp(float v){
#if __has_builtin(__builtin_amdgcn_mov_dpp)
    int i;
    i = __builtin_amdgcn_mov_dpp(__float_as_int(v), 0xB1, 0xF, 0xF, true);
    v += __int_as_float(i);
    i = __builtin_amdgcn_mov_dpp(__float_as_int(v), 0x4E, 0xF, 0xF, true);
    v += __int_as_float(i);
    i = __builtin_amdgcn_mov_dpp(__float_as_int(v), 0x141, 0xF, 0xF, true);
    v += __int_as_float(i);
    i = __builtin_amdgcn_mov_dpp(__float_as_int(v), 0x128, 0xF, 0xF, true);
    v += __int_as_float(i);
    return v;
#else
    v += __shfl_xor(v,1); v += __shfl_xor(v,2);
    v += __shfl_xor(v,4); v += __shfl_xor(v,8);
    return v;
#endif
}

// Fused 4-way 16-lane reduction: v_add_f32_dpp, round-robin for hazard spacing.
__device__ inline void red16dpp4(float& v0, float& v1, float& v2, float& v3){
#if defined(__gfx950__) || defined(__gfx942__) || defined(__gfx90a__)
    asm volatile(
        "s_nop 1\n\t"
        "v_add_f32_dpp %0, %0, %0 quad_perm:[1,0,3,2] row_mask:0xf bank_mask:0xf\n\t"
        "v_add_f32_dpp %1, %1, %1 quad_perm:[1,0,3,2] row_mask:0xf bank_mask:0xf\n\t"
        "v_add_f32_dpp %2, %2, %2 quad_perm:[1,0,3,2] row_mask:0xf bank_mask:0xf\n\t"
        "v_add_f32_dpp %3, %3, %3 quad_perm:[1,0,3,2] row_mask:0xf bank_mask:0xf\n\t"
        "v_add_f32_dpp %0, %0, %0 quad_perm:[2,3,0,1] row_mask:0xf bank_mask:0xf\n\t"
        "v_add_f32_dpp %1, %1, %1 quad_perm:[2,3,0,1] row_mask:0xf bank_mask:0xf\n\t"
        "v_add_f32_dpp %2, %2, %2 quad_perm:[2,3,0,1] row_mask:0xf bank_mask:0xf\n\t"
        "v_add_f32_dpp %3, %3, %3 quad_perm:[2,3,0,1] row_mask:0xf bank_mask:0xf\n\t"
        "v_add_f32_dpp %0, %0, %0 row_half_mirror row_mask:0xf bank_mask:0xf\n\t"
        "v_add_f32_dpp %1, %1, %1 row_half_mirror row_mask:0xf bank_mask:0xf\n\t"
        "v_add_f32_dpp %2, %2, %2 row_half_mirror row_mask:0xf bank_mask:0xf\n\t"
        "v_add_f32_dpp %3, %3, %3 row_half_mirror row_mask:0xf bank_mask:0xf\n\t"
        "v_add_f32_dpp %0, %0, %0 row_ror:8 row_mask:0xf bank_mask:0xf\n\t"
        "v_add_f32_dpp %1, %1, %1 row_ror:8 row_mask:0xf bank_mask:0xf\n\t"
        "v_add_f32_dpp %2, %2, %2 row_ror:8 row_mask:0xf bank_mask:0xf\n\t"
        "v_add_f32_dpp %3, %3, %3 row_ror:8 row_mask:0xf bank_mask:0xf"
        : "+v"(v0), "+v"(v1), "+v"(v2), "+v"(v3));
#else
    v0 = red16dpp(v0); v1 = red16dpp(v1); v2 = red16dpp(v2); v3 = red16dpp(v3);
#endif
}

#define ACCUM8(p0,p1,p2,p3,p4,p5,p6,p7,e,u) do { \
    p0 = fmaf(e, bf2f((unsigned short)((u).x&0xffffu)), p0); \
    p1 = fmaf(e, bf2f((unsigned short)((u).x>>16)),    p1); \
    p2 = fmaf(e, bf2f((unsigned short)((u).y&0xffffu)), p2); \
    p3 = fmaf(e, bf2f((unsigned short)((u).y>>16)),    p3); \
    p4 = fmaf(e, bf2f((unsigned short)((u).z&0xffffu)), p4); \
    p5 = fmaf(e, bf2f((unsigned short)((u).z>>16)),    p5); \
    p6 = fmaf(e, bf2f((unsigned short)((u).w&0xffffu)), p6); \
    p7 = fmaf(e, bf2f((unsigned short)((u).w>>16)),    p7); \
} while(0)

// ================= mega front-end: csrt | queryall | proj ==================
// blocks 0..255: CSR build + weight transpose   (per graph)
// blocks 256..511: query-side both layers        (per graph)
// blocks 512..2559: data proj (64 rows each) -> h_g bf16 + raw nrm2
#define SMEM_MEGA 11008
__global__ __launch_bounds__(256) void k_mega(
        const int* __restrict__ g_src, const int* __restrict__ g_dst,
        const float* __restrict__ Wg, const float* __restrict__ W1r,
        const float* __restrict__ W2r,
        unsigned short* __restrict__ WgT, unsigned short* __restrict__ W1aT,
        unsigned short* __restrict__ W2rT,
        unsigned short* __restrict__ csrc_g, int* __restrict__ off_g,
        float* __restrict__ degf, unsigned short* __restrict__ nodeperm,
        const float* __restrict__ X_q,
        const float* __restrict__ Wq, const float* __restrict__ bq,
        const int* __restrict__ q_src, const int* __restrict__ q_dst,
        const float* __restrict__ betas_q,
        float* __restrict__ Qv, float* __restrict__ cg2a,
        const float* __restrict__ X,
        const unsigned short* __restrict__ WgT_in,  // == WgT (read in proj path)
        const float* __restrict__ bg,
        unsigned short* __restrict__ h_g, float* __restrict__ nrm2){
    extern __shared__ __align__(16) char smem[];
    int bid = blockIdx.x, t = threadIdx.x;
    if (bid < B_){
        // ---------------- CSR + transpose ----------------
        int g = bid, lane = t & 63;
        int* cnt   = (int*)smem;            // 512
        int* woff  = (int*)(smem + 2048);   // 512
        int* gscan = (int*)(smem + 4096);   // 64
        int* dh    = (int*)(smem + 4352);   // 64
        int* dhoff = (int*)(smem + 4608);   // 64
        for (int idx = g*256 + t; idx < 73728; idx += 65536){
            if (idx < 8192){
                int k = idx >> 7, n = idx & 127; WgT[n*64 + k] = f2bf(Wg[idx]);
            } else if (idx < 40960){
                int i = idx - 8192; int l = i >> 14; int j = i & 16383;
                int k = j>>7, n = j&127;
                W1aT[l*16384 + n*128 + k] = f2bf(W1r[l*32768 + j]);
            } else {
                int i = idx - 40960; int l = i >> 14; int j = i & 16383;
                int k = j>>7, n = j&127;
                W2rT[l*16384 + n*128 + k] = f2bf(W2r[i]);
            }
        }
        int gbase = g*NPG; size_t ebase = (size_t)g*EPG;
        for (int n=t;n<NPG;n+=256) cnt[n]=0;
        if (t<64) dh[t]=0;
        __syncthreads();
        for (int i=t;i<EPG;i+=256){
            int d = g_dst[ebase+i]-gbase;
            atomicAdd(&cnt[d],1);
        }
        __syncthreads();
        if (t < 64){
            int s=0;
            #pragma unroll
            for (int j=0;j<8;j++) s += cnt[t*8+j];
            int v=s;
            #pragma unroll
            for (int o=1;o<64;o<<=1){ int u=__shfl_up(v,o); if (lane>=o) v+=u; }
            gscan[t]=v;
        }
        __syncthreads();
        for (int n=t;n<NPG;n+=256){
            int grp=n>>3; int base = grp?gscan[grp-1]:0;
            for (int j=grp*8;j<n;j++) base+=cnt[j];
            off_g[g*NPG+n]=base; woff[n]=base;
            degf[gbase+n] = cnt[n]>0 ? 1.f : 0.f;
            atomicAdd(&dh[cnt[n] < 63 ? cnt[n] : 63], 1);
        }
        __syncthreads();
        if (t < 64){
            int v = dh[t];
            #pragma unroll
            for (int o=1;o<64;o<<=1){ int u=__shfl_up(v,o); if (lane>=o) v+=u; }
            dhoff[t] = v - dh[t];   // exclusive
        }
        __syncthreads();
        for (int n=t;n<NPG;n+=256){
            int d = cnt[n] < 63 ? cnt[n] : 63;
            int pos = atomicAdd(&dhoff[d],1);
            nodeperm[g*NPG+pos] = (unsigned short)n;
        }
        __syncthreads();
        for (int i=t;i<EPG;i+=256){
            int s = g_src[ebase+i]-gbase;
            int d = g_dst[ebase+i]-gbase;
            int pos = atomicAdd(&woff[d],1);
            csrc_g[ebase+pos]=(unsigned short)s;
        }
    } else if (bid < 2*B_){
        // ---------------- query-side (both layers) ----------------
        int g = bid - B_, sl = t & 15;
        unsigned short* hqrows = (unsigned short*)smem;            // 4352
        float* xq              = (float*)(smem + 4352);            // 4096
        float* eq              = (float*)(smem + 8448);            // 512
        unsigned short* srcq   = (unsigned short*)(smem + 8960);   // 256
        unsigned short* dstq   = (unsigned short*)(smem + 9216);   // 256
        float* invq            = (float*)(smem + 9472);            // 64
        float* denq            = (float*)(smem + 9536);            // 64
        float* hqa             = (float*)(smem + 9600);            // 512
        float* cg2s            = (float*)(smem + 10112);           // 512
        unsigned int* emaskw   = (unsigned int*)(smem + 10624);    // 256
        float* QaccL           = (float*)(smem + 10880);           // 4
        for (int i=t;i<NQPG*64;i+=256) xq[i] = X_q[(size_t)g*NQPG*64 + i];
        if (t < EQPG){
            srcq[t] = (unsigned short)(q_src[(size_t)g*EQPG+t] - g*NQPG);
            dstq[t] = (unsigned short)(q_dst[(size_t)g*EQPG+t] - g*NQPG);
        }
        __syncthreads();
        {
            int r = t >> 4, c0 = sl*8;
            float v[8];
            #pragma unroll
            for (int j=0;j<8;j++) v[j] = bq[c0+j];
            for (int k=0;k<64;k++){
                float x = xq[r*64+k];
                const float* wr = Wq + k*128 + c0;
                #pragma unroll
                for (int j=0;j<8;j++) v[j] = fmaf(x, wr[j], v[j]);
            }
            uint4 uu;
            uu.x = (unsigned int)f2bf(v[0]) | ((unsigned int)f2bf(v[1])<<16);
            uu.y = (unsigned int)f2bf(v[2]) | ((unsigned int)f2bf(v[3])<<16);
            uu.z = (unsigned int)f2bf(v[4]) | ((unsigned int)f2bf(v[5])<<16);
            uu.w = (unsigned int)f2bf(v[6]) | ((unsigned int)f2bf(v[7])<<16);
            *(uint4*)(hqrows + r*HPITCH + sl*8) = uu;
        }
        int qn = t >> 4;
        for (int l=0; l<L_; l++){
            float beta_q = betas_q[l];
            if (t < NQPG) denq[t] = 0.f;
            if (t == 16) QaccL[0] = 0.f;
            if (t >= 32 && t < 96) emaskw[t-32] = 0u;
            if (t >= 128 && t < 256) cg2s[t-128] = 0.f;
            __syncthreads();
            // norms
            {
                uint4 u = *(const uint4*)(hqrows + qn*HPITCH + sl*8);
                float s = red16dpp(dot8(u,u));
                if (sl==0) invq[qn] = rsqrtf(s + 1e-24f);
            }
            __syncthreads();
            // edge logits + per-dst edge bitmask
            for (int e = qn; e < EQPG; e += 16){
                int s = srcq[e], d = dstq[e];
                uint4 us = *(const uint4*)(hqrows + s*HPITCH + sl*8);
                uint4 ud = *(const uint4*)(hqrows + d*HPITCH + sl*8);
                float v = red16dpp(dot8(us, ud));
                if (sl==0){
                    float ee = __expf(beta_q * v * invq[s] * invq[d]);
                    eq[e] = ee;
                    atomicAdd(&denq[d], ee);
                    atomicOr(&emaskw[d*4 + (e>>5)], 1u << (e & 31));
                }
            }
            __syncthreads();
            // aggregate via bitmask (ascending e order preserved)
            uint4 nq; nq.x=0; nq.y=0; nq.z=0; nq.w=0;
            {
                float wsum = denq[qn];
                if (wsum > 0.f){
                    float a0=0,a1=0,a2=0,a3=0,a4=0,a5=0,a6=0,a7=0;
                    #pragma unroll
                    for (int w=0;w<4;w++){
                        unsigned int m = emaskw[qn*4+w];
                        while (m){
                            int b = __ffs(m)-1; m &= m-1;
                            int e = w*32 + b;
                            float wg = eq[e];
                            int s = srcq[e];
                            uint4 u = *(const uint4*)(hqrows + s*HPITCH + sl*8);
                            ACCUM8(a0,a1,a2,a3,a4,a5,a6,a7, wg, u);
                        }
                    }
                    float iw = __frcp_rn(wsum);
                    nq.x = (unsigned int)f2bf(a0*iw) | ((unsigned int)f2bf(a1*iw)<<16);
                    nq.y = (unsigned int)f2bf(a2*iw) | ((unsigned int)f2bf(a3*iw)<<16);
                    nq.z = (unsigned int)f2bf(a4*iw) | ((unsigned int)f2bf(a5*iw)<<16);
                    nq.w = (unsigned int)f2bf(a6*iw) | ((unsigned int)f2bf(a7*iw)<<16);
                }
            }
            __syncthreads();
            *(uint4*)(hqrows + qn*HPITCH + sl*8) = nq;
            __syncthreads();
            // hqa + Q (wave-reduced)
            if (t < 128){
                float s = 0.f;
                for (int n=0;n<NQPG;n++) s += bf2f(hqrows[n*HPITCH + t]);
                hqa[t] = s;
                float qs = s*s;
                #pragma unroll
                for (int o=1;o<64;o<<=1) qs += __shfl_xor(qs, o);
                if ((t & 63) == 0) atomicAdd(&QaccL[0], qs);
            }
            __syncthreads();
            if (t == 0) Qv[l*B_+g] = QaccL[0];
            // cg2 = W1[128:256]^T @ hqa
            {
                int jj = t & 127, kc = t >> 7;
                const float* Wl = W1r + (size_t)l*32768;
                float p = 0.f;
                for (int k = kc*64; k < kc*64+64; k++)
                    p = fmaf(hqa[k], Wl[(size_t)(128+k)*128 + jj], p);
                atomicAdd(&cg2s[jj], p);
            }
            __syncthreads();
            if (t < 128) cg2a[((size_t)l*B_+g)*128 + t] = cg2s[t];
            __syncthreads();
        }
    } else {
        // ---------------- data proj -> h_g + raw nrm2 ----------------
        const int K = 64;
        int blk = bid - 2*B_;
        int wave = t >> 6, lane = t & 63;
        int quad = lane >> 4, l16 = lane & 15;
        int wrow = blk*64 + wave*16;
        floatx4 acc[8];
        #pragma unroll
        for (int t8=0;t8<8;t8++){
            #pragma unroll
            for (int r=0;r<4;r++) acc[t8][r]=0.f;
        }
        #pragma unroll
        for (int ks = 0; ks < 2; ks++){
            int koff = ks*32 + quad*8;
            const float* ap = X + (size_t)(wrow+l16)*K + koff;
            short8 a;
            #pragma unroll
            for (int j=0;j<8;j++) a[j] = (short)f2bf(ap[j]);
            #pragma unroll
            for (int t8=0;t8<8;t8++){
                short8 b = *(const short8*)(WgT_in + (size_t)(t8*16+l16)*K + koff);
                acc[t8] = __builtin_amdgcn_mfma_f32_16x16x32_bf16(a, b, acc[t8], 0,0,0);
            }
        }
        float ss[4] = {0.f,0.f,0.f,0.f};
        #pragma unroll
        for (int t8=0;t8<8;t8++){
            int col = t8*16 + l16;
            float bv = bg[col];
            #pragma unroll
            for (int r=0;r<4;r++){
                float v = acc[t8][r] + bv;
                h_g[(size_t)(wrow + quad*4 + r)*128 + col] = f2bf(v);
                ss[r] += v*v;
            }
        }
        #pragma unroll
        for (int r=0;r<4;r++){
            #pragma unroll
            for (int o=1;o<16;o<<=1) ss[r] += __shfl_xor(ss[r], o);
        }
        if (l16==0){
            #pragma unroll
            for (int r=0;r<4;r++) nrm2[wrow + quad*4 + r] = ss[r];
        }
    }
}

// ====== persistent per-graph back-end: BOTH layers (edge+MLP) + predictor ==
// Per layer:
//   phase-1 LDS: hrows 0..139264 | inv ..141312 | ssrc ..149504 |
//                offc ..151556 | nprm ..152580 (pad 152592)
//   phase-2 LDS (hrows dead): W1s 0..34816 | W2s ..69632 | h1 ..139264 |
//                inv region reused: raw next-layer nrm2 (l=0) / hsum+red2 (pred)
//   ssrc/offc/nprm survive phase-2 and layer transitions (region untouched).
#define SMEM_GM 152592
#define CIDX(x) ((x) < je1 ? (x) : je1)
#define ROW(i) (*(const uint4*)(hrows + (i)*HPITCH + sl*8))
#define COMP4(U0,U1,U2,U3,I0,I1,I2,I3,JB) do { \
    float v0 = dot8q(U0, ud, Qs); \
    float v1 = dot8q(U1, ud, Qs); \
    float v2 = dot8q(U2, ud, Qs); \
    float v3 = dot8q(U3, ud, Qs); \
    red16dpp4(v0, v1, v2, v3); \
    float e0 = FEXP2(v0 * I0 * bn); \
    float e1 = FEXP2(v1 * I1 * bn); \
    float e2 = FEXP2(v2 * I2 * bn); \
    float e3 = FEXP2(v3 * I3 * bn); \
    if ((JB)+1 >= jend) e1 = 0.f; \
    if ((JB)+2 >= jend) e2 = 0.f; \
    if ((JB)+3 >= jend) e3 = 0.f; \
    ws += (e0 + e1) + (e2 + e3); \
    ax += e0 * bf2x2(U0.x); ay += e0 * bf2x2(U0.y); \
    az += e0 * bf2x2(U0.z); aw += e0 * bf2x2(U0.w); \
    ax += e1 * bf2x2(U1.x); ay += e1 * bf2x2(U1.y); \
    az += e1 * bf2x2(U1.z); aw += e1 * bf2x2(U1.w); \
    ax += e2 * bf2x2(U2.x); ay += e2 * bf2x2(U2.y); \
    az += e2 * bf2x2(U2.z); aw += e2 * bf2x2(U2.w); \
    ax += e3 * bf2x2(U3.x); ay += e3 * bf2x2(U3.y); \
    az += e3 * bf2x2(U3.z); aw += e3 * bf2x2(U3.w); \
} while(0)
__global__ __launch_bounds__(1024) void k_uber2(
        unsigned short* hbuf,                 // h_g: read (stage) + write (MLP l=0)
        const float* __restrict__ nrm2g,
        const float* __restrict__ betas_g,
        const float* __restrict__ Qv,
        const unsigned short* __restrict__ csrc_g,
        const int* __restrict__ off_g,
        const unsigned short* __restrict__ nodeperm,
        unsigned short* __restrict__ aout,
        const unsigned short* __restrict__ W1aT, const float* __restrict__ b1r,
        const float* __restrict__ cg2a,
        const unsigned short* __restrict__ W2rT, const float* __restrict__ b2r,
        const float* __restrict__ Wp1, const float* __restrict__ bp1,
        const float* __restrict__ Wp2, const float* __restrict__ bp2,
        float* __restrict__ y){
    extern __shared__ __align__(16) char smem[];
    unsigned short* hrows = (unsigned short*)smem;
    float* inv            = (float*)(smem + 139264);
    unsigned short* ssrc  = (unsigned short*)(smem + 141312);
    int* offc             = (int*)(smem + 149504);
    unsigned short* nprm  = (unsigned short*)(smem + 151556);
    int g = blockIdx.x, t = threadIdx.x;
    int group = t >> 4, sl = t & 15;
    int gbase = g*NPG;
    size_t ebase = (size_t)g*EPG;
    int wave = t>>6, lane = t&63, quad = lane>>4, l16 = lane&15;
    float psum[8];
    #pragma unroll
    for (int j=0;j<8;j++) psum[j] = 0.f;
    for (int l=0; l<L_; l++){
        float Q = Qv[l*B_+g];
        float beta_g = betas_g[l];
        // ---- stage ----
        for (int i=t; i<8192; i+=1024){
            int row = i >> 4, col = i & 15;
            *(uint4*)(hrows + row*HPITCH + col*8) =
                *(const uint4*)(hbuf + (size_t)(gbase+row)*128 + col*8);
        }
        if (l == 0){
            for (int n=t; n<NPG; n+=1024){
                inv[n] = rsqrtf(nrm2g[gbase+n] + Q + 1e-24f);
                nprm[n] = nodeperm[g*NPG+n];
            }
            for (int i=t; i<EPG; i+=1024) ssrc[i] = csrc_g[ebase+i];
            for (int n=t; n<=NPG; n+=1024) offc[n] = (n<NPG) ? off_g[g*NPG+n] : EPG;
        } else {
            // inv holds raw nrm2 written by previous layer's MLP (LDS-resident)
            for (int n=t; n<NPG; n+=1024) inv[n] = rsqrtf(inv[n] + Q + 1e-24f);
        }
        __syncthreads();
        float Qs = Q * 0.0625f;   // folded into dot init; 16-lane sum restores +Q
        // ---- edge loop (R7-proven body) -> aout ----
        for (int idx = group; idx < NPG; idx += 64){
            int n = nprm[idx];
            int o = offc[n];
            int jend = offc[n+1];
            uint4 ov;
            if (jend > o){
                uint4 ud = *(const uint4*)(hrows + n*HPITCH + sl*8);
                float bn = beta_g * inv[n] * LOG2E_;
                float ws = 0.f;
                float2v ax; ax.x=0.f; ax.y=0.f;
                float2v ay = ax, az = ax, aw = ax;
                int je1 = jend - 1;
                int iA0 = ssrc[o];
                int iA1 = ssrc[CIDX(o+1)];
                int iA2 = ssrc[CIDX(o+2)];
                int iA3 = ssrc[CIDX(o+3)];
                uint4 uA0 = ROW(iA0);
                uint4 uA1 = ROW(iA1);
                uint4 uA2 = ROW(iA2);
                uint4 uA3 = ROW(iA3);
                float vA0 = inv[iA0], vA1 = inv[iA1], vA2 = inv[iA2], vA3 = inv[iA3];
                int iB0 = ssrc[CIDX(o+4)];
                int iB1 = ssrc[CIDX(o+5)];
                int iB2 = ssrc[CIDX(o+6)];
                int iB3 = ssrc[CIDX(o+7)];
                int j = o;
                for (;;){
                    uint4 uB0 = ROW(iB0);
                    uint4 uB1 = ROW(iB1);
                    uint4 uB2 = ROW(iB2);
                    uint4 uB3 = ROW(iB3);
                    float vB0 = inv[iB0], vB1 = inv[iB1], vB2 = inv[iB2], vB3 = inv[iB3];
                    iA0 = ssrc[CIDX(j+8)];
                    iA1 = ssrc[CIDX(j+9)];
                    iA2 = ssrc[CIDX(j+10)];
                    iA3 = ssrc[CIDX(j+11)];
                    COMP4(uA0,uA1,uA2,uA3, vA0,vA1,vA2,vA3, j);
                    j += 4; if (j >= jend) break;
                    uA0 = ROW(iA0);
                    uA1 = ROW(iA1);
                    uA2 = ROW(iA2);
                    uA3 = ROW(iA3);
                    vA0 = inv[iA0]; vA1 = inv[iA1]; vA2 = inv[iA2]; vA3 = inv[iA3];
                    iB0 = ssrc[CIDX(j+8)];
                    iB1 = ssrc[CIDX(j+9)];
                    iB2 = ssrc[CIDX(j+10)];
                    iB3 = ssrc[CIDX(j+11)];
                    COMP4(uB0,uB1,uB2,uB3, vB0,vB1,vB2,vB3, j);
                    j += 4; if (j >= jend) break;
                }
                float iw = __frcp_rn(ws);
                ov.x = (unsigned int)f2bf(ax.x*iw) | ((unsigned int)f2bf(ax.y*iw)<<16);
                ov.y = (unsigned int)f2bf(ay.x*iw) | ((unsigned int)f2bf(ay.y*iw)<<16);
                ov.z = (unsigned int)f2bf(az.x*iw) | ((unsigned int)f2bf(az.y*iw)<<16);
                ov.w = (unsigned int)f2bf(aw.x*iw) | ((unsigned int)f2bf(aw.y*iw)<<16);
            } else {
                ov.x=0; ov.y=0; ov.z=0; ov.w=0;
            }
            *(uint4*)(aout + (size_t)(gbase+n)*128 + sl*8) = ov;
        }
        __syncthreads();   // hrows reads + aout writes drained
        // ---- MLP phase: all 16 waves, 256 rows/pass, 2 passes ----
        unsigned short* W1s = (unsigned short*)smem;        // 128 x 136
        unsigned short* W2s = W1s + 128*136;                // 128 x 136
        unsigned short* h1  = W2s + 128*136;                // 256 x 136
        float* invf = (float*)(smem + 139264);              // raw nrm2 out (l=0)
        const unsigned short* W1t = W1aT + l*16384;
        const unsigned short* W2t = W2rT + l*16384;
        const float* b1 = b1r + l*128;
        const float* b2 = b2r + l*128;
        const float* cg = cg2a + ((size_t)l*B_ + g)*128;
        #pragma unroll
        for (int p=0;p<2;p++){
            int flat = p*8192 + t*8;
            int n = flat>>7, k = flat&127;
            *(uint4*)(W1s + n*136 + k) = *(const uint4*)(W1t + n*128 + k);
            *(uint4*)(W2s + n*136 + k) = *(const uint4*)(W2t + n*128 + k);
        }
        __syncthreads();
        const int last = (l == L_-1);
        for (int it=0; it<2; it++){
            int rowb = it*256 + wave*16;   // graph-local row base for this wave
            short8 af[4];
            #pragma unroll
            for (int ks=0;ks<4;ks++)
                af[ks] = *(const short8*)(aout + (size_t)(gbase+rowb+l16)*128 + ks*32 + quad*8);
            floatx4 acc[8];
            #pragma unroll
            for (int t8=0;t8<8;t8++){
                #pragma unroll
                for (int r=0;r<4;r++) acc[t8][r]=0.f;
            }
            #pragma unroll
            for (int ks=0;ks<4;ks++){
                int koff = ks*32 + quad*8;
                #pragma unroll
                for (int t8=0;t8<8;t8++){
                    short8 b = *(const short8*)(W1s + (t8*16+l16)*136 + koff);
                    acc[t8] = __builtin_amdgcn_mfma_f32_16x16x32_bf16(af[ks], b, acc[t8], 0,0,0);
                }
            }
            int lrow = wave*16;            // h1-local row base
            #pragma unroll
            for (int t8=0;t8<8;t8++){
                int col = t8*16 + l16;
                float bv = b1[col];
                float cv = cg[col];
                #pragma unroll
                for (int r=0;r<4;r++){
                    int row = rowb + quad*4 + r;
                    float dgv = (offc[row+1] > offc[row]) ? 1.f : 0.f;
                    float v = acc[t8][r] + bv + dgv*cv;
                    v = v > 0.f ? v : 0.f;
                    h1[(lrow + quad*4 + r)*136 + col] = f2bf(v);
                }
            }
            __syncthreads();
            short8 hf[4];
            #pragma unroll
            for (int ks=0;ks<4;ks++)
                hf[ks] = *(const short8*)(h1 + (lrow+l16)*136 + ks*32 + quad*8);
            floatx4 acc2[8];
            #pragma unroll
            for (int t8=0;t8<8;t8++){
                #pragma unroll
                for (int r=0;r<4;r++) acc2[t8][r]=0.f;
            }
            #pragma unroll
            for (int ks=0;ks<4;ks++){
                int koff = ks*32 + quad*8;
                #pragma unroll
                for (int t8=0;t8<8;t8++){
                    short8 b = *(const short8*)(W2s + (t8*16+l16)*136 + koff);
                    acc2[t8] = __builtin_amdgcn_mfma_f32_16x16x32_bf16(hf[ks], b, acc2[t8], 0,0,0);
                }
            }
            float ss[4] = {0.f,0.f,0.f,0.f};
            #pragma unroll
            for (int t8=0;t8<8;t8++){
                int col = t8*16 + l16;
                float bv = b2[col];
                #pragma unroll
                for (int r=0;r<4;r++){
                    float v = acc2[t8][r] + bv;
                    if (last){
                        psum[t8] += v;
                    } else {
                        hbuf[(size_t)(gbase + rowb + quad*4 + r)*128 + col] = f2bf(v);
                        ss[r] += v*v;
                    }
                }
            }
            if (!last){
                #pragma unroll
                for (int r=0;r<4;r++){
                    #pragma unroll
                    for (int o=1;o<16;o<<=1) ss[r] += __shfl_xor(ss[r], o);
                }
                if (l16==0){
                    #pragma unroll
                    for (int r=0;r<4;r++)
                        invf[rowb + quad*4 + r] = ss[r];   // raw nrm2 -> next layer
                }
            }
            __syncthreads();
        }
    }
    // ---- fused predictor ----
    {
        float* hsum = (float*)(smem + 139264);
        float* red2 = hsum + 128;
        if (t < 128) hsum[t] = 0.f;
        __syncthreads();
        #pragma unroll
        for (int j=0;j<8;j++){
            psum[j] += __shfl_xor(psum[j], 16);
            psum[j] += __shfl_xor(psum[j], 32);
        }
        if (lane < 16){
            #pragma unroll
            for (int j=0;j<8;j++) atomicAdd(&hsum[j*16 + lane], psum[j]);
        }
        __syncthreads();
        if (t < 128){
            float acc = bp1[t];
            for (int k=0;k<128;k++) acc += hsum[k]*Wp1[k*128+t];
            acc = fmaxf(acc, 0.f);
            red2[t] = acc * Wp2[t];
        }
        __syncthreads();
        for (int s2=64; s2>0; s2>>=1){
            if (t<s2) red2[t]+=red2[t+s2];
            __syncthreads();
        }
        if (t==0) y[g] = red2[0] + bp2[0];
    }
}

extern "C" void kernel_launch(void* const* d_in, const int* in_sizes, int n_in,
                              void* d_out, int out_size, void* d_ws, size_t ws_size,
                              hipStream_t stream) {
    const float* X    = (const float*)d_in[0];
    const float* X_q  = (const float*)d_in[1];
    const int* g_src = (const int*)d_in[2];
    const int* g_dst = (const int*)d_in[3];
    const int* q_src = (const int*)d_in[5];
    const int* q_dst = (const int*)d_in[6];
    const float* Wg   = (const float*)d_in[8];
    const float* bg   = (const float*)d_in[9];
    const float* Wq   = (const float*)d_in[10];
    const float* bq   = (const float*)d_in[11];
    const float* betas_g = (const float*)d_in[12];
    const float* betas_q = (const float*)d_in[13];
    const float* W1r  = (const float*)d_in[14];
    const float* b1r  = (const float*)d_in[15];
    const float* W2r  = (const float*)d_in[16];
    const float* b2r  = (const float*)d_in[17];
    const float* Wp1  = (const float*)d_in[18];
    const float* bp1  = (const float*)d_in[19];
    const float* Wp2  = (const float*)d_in[20];
    const float* bp2  = (const float*)d_in[21];

    uint8_t* w = (uint8_t*)d_ws;
    unsigned short* h_g  = (unsigned short*)w;    w += (size_t)NG*128*2;
    unsigned short* aout = (unsigned short*)w;    w += (size_t)NG*128*2;
    float* nrm2  = (float*)w;                     w += (size_t)NG*4;
    float* degf  = (float*)w;                     w += (size_t)NG*4;
    float* Qv    = (float*)w;                     w += (size_t)L_*B_*4;
    float* cg2a  = (float*)w;                     w += (size_t)L_*B_*128*4;
    unsigned short* WgT   = (unsigned short*)w;   w += 8192*2;
    unsigned short* W1aT  = (unsigned short*)w;   w += 2*16384*2;
    unsigned short* W2rT  = (unsigned short*)w;   w += 2*16384*2;
    unsigned short* csrc_g = (unsigned short*)w;  w += (size_t)B_*EPG*2;
    unsigned short* nodeperm = (unsigned short*)w; w += (size_t)B_*NPG*2;
    int* off_g = (int*)w;                         w += (size_t)B_*NPG*4;

    static bool attr_done = false;
    if (!attr_done){
        hipFuncSetAttribute((const void*)k_uber2,
                            hipFuncAttributeMaxDynamicSharedMemorySize, SMEM_GM);
        attr_done = true;
    }

    // front-end: csrt (256) | queryall (256) | proj (2048) in one launch
    k_mega<<<2*B_ + NG/64, 256, SMEM_MEGA, stream>>>(
        g_src, g_dst, Wg, W1r, W2r, WgT, W1aT, W2rT,
        csrc_g, off_g, degf, nodeperm,
        X_q, Wq, bq, q_src, q_dst, betas_q, Qv, cg2a,
        X, WgT, bg, h_g, nrm2);
    // back-end: one persistent block per graph, both layers + predictor
    k_uber2<<<B_, 1024, SMEM_GM, stream>>>(
        h_g, nrm2, betas_g, Qv, csrc_g, off_g, nodeperm, aout,
        W1aT, b1r, cg2a, W2rT, b2r,
        Wp1, bp1, Wp2, bp2, (float*)d_out);
}

// Round 14
// 259.006 us; speedup vs baseline: 1.0728x; 1.0728x over previous
//
#include <hip/hip_runtime.h>
#include <stdint.h>

#define B_   256
#define NPG  512
#define NG   131072
#define EPG  4096
#define NQPG 16
#define NQ   4096
#define EQPG 128
#define L_   2
#define HPITCH 136   // LDS row pitch in shorts (272 B)

typedef __attribute__((ext_vector_type(8))) short short8;
typedef __attribute__((ext_vector_type(4))) float floatx4;
typedef __attribute__((ext_vector_type(2))) float float2v;

__device__ inline float bf2f(unsigned short u){
    union { unsigned int i; float f; } x; x.i = ((unsigned int)u) << 16; return x.f;
}
__device__ inline unsigned short f2bf(float f){
    union { float f; unsigned int i; } x; x.f = f;
    unsigned int r = x.i + 0x7fff + ((x.i >> 16) & 1);  // RNE
    return (unsigned short)(r >> 16);
}
// unpack u32 (2×bf16) -> float2v {lo, hi}
__device__ inline float2v bf2x2(unsigned int u){
    union { unsigned int i; float f; } lo, hi;
    lo.i = u << 16; hi.i = u & 0xffff0000u;
    float2v r; r.x = lo.f; r.y = hi.f; return r;
}
__device__ inline float d2(unsigned int a, unsigned int b, float c){
#if __has_builtin(__builtin_amdgcn_fdot2_f32_bf16)
    typedef __attribute__((ext_vector_type(2))) __bf16 bf16x2;
    union { unsigned int u; bf16x2 v; } xa, xb;
    xa.u = a; xb.u = b;
    return __builtin_amdgcn_fdot2_f32_bf16(xa.v, xb.v, c, false);
#else
    union { unsigned int u; float f; } la, ha, lb, hb;
    la.u = a << 16; ha.u = a & 0xffff0000u;
    lb.u = b << 16; hb.u = b & 0xffff0000u;
    return fmaf(la.f, lb.f, fmaf(ha.f, hb.f, c));
#endif
}
__device__ inline float dot8(uint4 a, uint4 b){
    return d2(a.x,b.x, d2(a.y,b.y, d2(a.z,b.z, d2(a.w,b.w, 0.f))));
}
__device__ inline float dot8q(uint4 a, uint4 b, float c0){
    return d2(a.x,b.x, d2(a.y,b.y, d2(a.z,b.z, d2(a.w,b.w, c0))));
}

#if __has_builtin(__builtin_amdgcn_exp2f)
#define FEXP2(x) __builtin_amdgcn_exp2f(x)
#else
#define FEXP2(x) __expf((x) * 0.6931471805599453f)
#endif
#define LOG2E_ 1.4426950408889634f

// 16-lane all-reduce sum via DPP (VALU pipe).
__device__ inline float red16dpp(float v){
#if __has_builtin(__builtin_amdgcn_mov_dpp)
    int i;
    i = __builtin_amdgcn_mov_dpp(__float_as_int(v), 0xB1, 0xF, 0xF, true);
    v += __int_as_float(i);
    i = __builtin_amdgcn_mov_dpp(__float_as_int(v), 0x4E, 0xF, 0xF, true);
    v += __int_as_float(i);
    i = __builtin_amdgcn_mov_dpp(__float_as_int(v), 0x141, 0xF, 0xF, true);
    v += __int_as_float(i);
    i = __builtin_amdgcn_mov_dpp(__float_as_int(v), 0x128, 0xF, 0xF, true);
    v += __int_as_float(i);
    return v;
#else
    v += __shfl_xor(v,1); v += __shfl_xor(v,2);
    v += __shfl_xor(v,4); v += __shfl_xor(v,8);
    return v;
#endif
}

// Fused 4-way 16-lane reduction: v_add_f32_dpp, round-robin for hazard spacing.
__device__ inline void red16dpp4(float& v0, float& v1, float& v2, float& v3){
#if defined(__gfx950__) || defined(__gfx942__) || defined(__gfx90a__)
    asm volatile(
        "s_nop 1\n\t"
        "v_add_f32_dpp %0, %0, %0 quad_perm:[1,0,3,2] row_mask:0xf bank_mask:0xf\n\t"
        "v_add_f32_dpp %1, %1, %1 quad_perm:[1,0,3,2] row_mask:0xf bank_mask:0xf\n\t"
        "v_add_f32_dpp %2, %2, %2 quad_perm:[1,0,3,2] row_mask:0xf bank_mask:0xf\n\t"
        "v_add_f32_dpp %3, %3, %3 quad_perm:[1,0,3,2] row_mask:0xf bank_mask:0xf\n\t"
        "v_add_f32_dpp %0, %0, %0 quad_perm:[2,3,0,1] row_mask:0xf bank_mask:0xf\n\t"
        "v_add_f32_dpp %1, %1, %1 quad_perm:[2,3,0,1] row_mask:0xf bank_mask:0xf\n\t"
        "v_add_f32_dpp %2, %2, %2 quad_perm:[2,3,0,1] row_mask:0xf bank_mask:0xf\n\t"
        "v_add_f32_dpp %3, %3, %3 quad_perm:[2,3,0,1] row_mask:0xf bank_mask:0xf\n\t"
        "v_add_f32_dpp %0, %0, %0 row_half_mirror row_mask:0xf bank_mask:0xf\n\t"
        "v_add_f32_dpp %1, %1, %1 row_half_mirror row_mask:0xf bank_mask:0xf\n\t"
        "v_add_f32_dpp %2, %2, %2 row_half_mirror row_mask:0xf bank_mask:0xf\n\t"
        "v_add_f32_dpp %3, %3, %3 row_half_mirror row_mask:0xf bank_mask:0xf\n\t"
        "v_add_f32_dpp %0, %0, %0 row_ror:8 row_mask:0xf bank_mask:0xf\n\t"
        "v_add_f32_dpp %1, %1, %1 row_ror:8 row_mask:0xf bank_mask:0xf\n\t"
        "v_add_f32_dpp %2, %2, %2 row_ror:8 row_mask:0xf bank_mask:0xf\n\t"
        "v_add_f32_dpp %3, %3, %3 row_ror:8 row_mask:0xf bank_mask:0xf"
        : "+v"(v0), "+v"(v1), "+v"(v2), "+v"(v3));
#else
    v0 = red16dpp(v0); v1 = red16dpp(v1); v2 = red16dpp(v2); v3 = red16dpp(v3);
#endif
}

#define ACCUM8(p0,p1,p2,p3,p4,p5,p6,p7,e,u) do { \
    p0 = fmaf(e, bf2f((unsigned short)((u).x&0xffffu)), p0); \
    p1 = fmaf(e, bf2f((unsigned short)((u).x>>16)),    p1); \
    p2 = fmaf(e, bf2f((unsigned short)((u).y&0xffffu)), p2); \
    p3 = fmaf(e, bf2f((unsigned short)((u).y>>16)),    p3); \
    p4 = fmaf(e, bf2f((unsigned short)((u).z&0xffffu)), p4); \
    p5 = fmaf(e, bf2f((unsigned short)((u).z>>16)),    p5); \
    p6 = fmaf(e, bf2f((unsigned short)((u).w&0xffffu)), p6); \
    p7 = fmaf(e, bf2f((unsigned short)((u).w>>16)),    p7); \
} while(0)

// ================= mega front-end: csrt | queryall | proj ==================
// blocks 0..255: CSR build + weight transpose   (per graph)
// blocks 256..511: query-side both layers        (per graph)
// blocks 512..2559: data proj (64 rows each) -> h_g bf16 + raw nrm2
#define SMEM_MEGA 11008
__global__ __launch_bounds__(256) void k_mega(
        const int* __restrict__ g_src, const int* __restrict__ g_dst,
        const float* __restrict__ Wg, const float* __restrict__ W1r,
        const float* __restrict__ W2r,
        unsigned short* __restrict__ WgT, unsigned short* __restrict__ W1aT,
        unsigned short* __restrict__ W2rT,
        unsigned short* __restrict__ csrc_g, int* __restrict__ off_g,
        float* __restrict__ degf, unsigned short* __restrict__ nodeperm,
        const float* __restrict__ X_q,
        const float* __restrict__ Wq, const float* __restrict__ bq,
        const int* __restrict__ q_src, const int* __restrict__ q_dst,
        const float* __restrict__ betas_q,
        float* __restrict__ Qv, float* __restrict__ cg2a,
        const float* __restrict__ X,
        const unsigned short* __restrict__ WgT_in,  // == WgT (read in proj path)
        const float* __restrict__ bg,
        unsigned short* __restrict__ h_g, float* __restrict__ nrm2){
    extern __shared__ __align__(16) char smem[];
    int bid = blockIdx.x, t = threadIdx.x;
    if (bid < B_){
        // ---------------- CSR + transpose ----------------
        int g = bid, lane = t & 63;
        int* cnt   = (int*)smem;            // 512
        int* woff  = (int*)(smem + 2048);   // 512
        int* gscan = (int*)(smem + 4096);   // 64
        int* dh    = (int*)(smem + 4352);   // 64
        int* dhoff = (int*)(smem + 4608);   // 64
        for (int idx = g*256 + t; idx < 73728; idx += 65536){
            if (idx < 8192){
                int k = idx >> 7, n = idx & 127; WgT[n*64 + k] = f2bf(Wg[idx]);
            } else if (idx < 40960){
                int i = idx - 8192; int l = i >> 14; int j = i & 16383;
                int k = j>>7, n = j&127;
                W1aT[l*16384 + n*128 + k] = f2bf(W1r[l*32768 + j]);
            } else {
                int i = idx - 40960; int l = i >> 14; int j = i & 16383;
                int k = j>>7, n = j&127;
                W2rT[l*16384 + n*128 + k] = f2bf(W2r[i]);
            }
        }
        int gbase = g*NPG; size_t ebase = (size_t)g*EPG;
        for (int n=t;n<NPG;n+=256) cnt[n]=0;
        if (t<64) dh[t]=0;
        __syncthreads();
        for (int i=t;i<EPG;i+=256){
            int d = g_dst[ebase+i]-gbase;
            atomicAdd(&cnt[d],1);
        }
        __syncthreads();
        if (t < 64){
            int s=0;
            #pragma unroll
            for (int j=0;j<8;j++) s += cnt[t*8+j];
            int v=s;
            #pragma unroll
            for (int o=1;o<64;o<<=1){ int u=__shfl_up(v,o); if (lane>=o) v+=u; }
            gscan[t]=v;
        }
        __syncthreads();
        for (int n=t;n<NPG;n+=256){
            int grp=n>>3; int base = grp?gscan[grp-1]:0;
            for (int j=grp*8;j<n;j++) base+=cnt[j];
            off_g[g*NPG+n]=base; woff[n]=base;
            degf[gbase+n] = cnt[n]>0 ? 1.f : 0.f;
            atomicAdd(&dh[cnt[n] < 63 ? cnt[n] : 63], 1);
        }
        __syncthreads();
        if (t < 64){
            int v = dh[t];
            #pragma unroll
            for (int o=1;o<64;o<<=1){ int u=__shfl_up(v,o); if (lane>=o) v+=u; }
            dhoff[t] = v - dh[t];   // exclusive
        }
        __syncthreads();
        for (int n=t;n<NPG;n+=256){
            int d = cnt[n] < 63 ? cnt[n] : 63;
            int pos = atomicAdd(&dhoff[d],1);
            nodeperm[g*NPG+pos] = (unsigned short)n;
        }
        __syncthreads();
        for (int i=t;i<EPG;i+=256){
            int s = g_src[ebase+i]-gbase;
            int d = g_dst[ebase+i]-gbase;
            int pos = atomicAdd(&woff[d],1);
            csrc_g[ebase+pos]=(unsigned short)s;
        }
    } else if (bid < 2*B_){
        // ---------------- query-side (both layers) ----------------
        int g = bid - B_, sl = t & 15;
        unsigned short* hqrows = (unsigned short*)smem;            // 4352
        float* xq              = (float*)(smem + 4352);            // 4096
        float* eq              = (float*)(smem + 8448);            // 512
        unsigned short* srcq   = (unsigned short*)(smem + 8960);   // 256
        unsigned short* dstq   = (unsigned short*)(smem + 9216);   // 256
        float* invq            = (float*)(smem + 9472);            // 64
        float* denq            = (float*)(smem + 9536);            // 64
        float* hqa             = (float*)(smem + 9600);            // 512
        float* cg2s            = (float*)(smem + 10112);           // 512
        unsigned int* emaskw   = (unsigned int*)(smem + 10624);    // 256
        float* QaccL           = (float*)(smem + 10880);           // 4
        for (int i=t;i<NQPG*64;i+=256) xq[i] = X_q[(size_t)g*NQPG*64 + i];
        if (t < EQPG){
            srcq[t] = (unsigned short)(q_src[(size_t)g*EQPG+t] - g*NQPG);
            dstq[t] = (unsigned short)(q_dst[(size_t)g*EQPG+t] - g*NQPG);
        }
        __syncthreads();
        {
            int r = t >> 4, c0 = sl*8;
            float v[8];
            #pragma unroll
            for (int j=0;j<8;j++) v[j] = bq[c0+j];
            for (int k=0;k<64;k++){
                float x = xq[r*64+k];
                const float* wr = Wq + k*128 + c0;
                #pragma unroll
                for (int j=0;j<8;j++) v[j] = fmaf(x, wr[j], v[j]);
            }
            uint4 uu;
            uu.x = (unsigned int)f2bf(v[0]) | ((unsigned int)f2bf(v[1])<<16);
            uu.y = (unsigned int)f2bf(v[2]) | ((unsigned int)f2bf(v[3])<<16);
            uu.z = (unsigned int)f2bf(v[4]) | ((unsigned int)f2bf(v[5])<<16);
            uu.w = (unsigned int)f2bf(v[6]) | ((unsigned int)f2bf(v[7])<<16);
            *(uint4*)(hqrows + r*HPITCH + sl*8) = uu;
        }
        int qn = t >> 4;
        for (int l=0; l<L_; l++){
            float beta_q = betas_q[l];
            if (t < NQPG) denq[t] = 0.f;
            if (t == 16) QaccL[0] = 0.f;
            if (t >= 32 && t < 96) emaskw[t-32] = 0u;
            if (t >= 128 && t < 256) cg2s[t-128] = 0.f;
            __syncthreads();
            // norms
            {
                uint4 u = *(const uint4*)(hqrows + qn*HPITCH + sl*8);
                float s = red16dpp(dot8(u,u));
                if (sl==0) invq[qn] = rsqrtf(s + 1e-24f);
            }
            __syncthreads();
            // edge logits + per-dst edge bitmask
            for (int e = qn; e < EQPG; e += 16){
                int s = srcq[e], d = dstq[e];
                uint4 us = *(const uint4*)(hqrows + s*HPITCH + sl*8);
                uint4 ud = *(const uint4*)(hqrows + d*HPITCH + sl*8);
                float v = red16dpp(dot8(us, ud));
                if (sl==0){
                    float ee = __expf(beta_q * v * invq[s] * invq[d]);
                    eq[e] = ee;
                    atomicAdd(&denq[d], ee);
                    atomicOr(&emaskw[d*4 + (e>>5)], 1u << (e & 31));
                }
            }
            __syncthreads();
            // aggregate via bitmask (ascending e order preserved)
            uint4 nq; nq.x=0; nq.y=0; nq.z=0; nq.w=0;
            {
                float wsum = denq[qn];
                if (wsum > 0.f){
                    float a0=0,a1=0,a2=0,a3=0,a4=0,a5=0,a6=0,a7=0;
                    #pragma unroll
                    for (int w=0;w<4;w++){
                        unsigned int m = emaskw[qn*4+w];
                        while (m){
                            int b = __ffs(m)-1; m &= m-1;
                            int e = w*32 + b;
                            float wg = eq[e];
                            int s = srcq[e];
                            uint4 u = *(const uint4*)(hqrows + s*HPITCH + sl*8);
                            ACCUM8(a0,a1,a2,a3,a4,a5,a6,a7, wg, u);
                        }
                    }
                    float iw = __frcp_rn(wsum);
                    nq.x = (unsigned int)f2bf(a0*iw) | ((unsigned int)f2bf(a1*iw)<<16);
                    nq.y = (unsigned int)f2bf(a2*iw) | ((unsigned int)f2bf(a3*iw)<<16);
                    nq.z = (unsigned int)f2bf(a4*iw) | ((unsigned int)f2bf(a5*iw)<<16);
                    nq.w = (unsigned int)f2bf(a6*iw) | ((unsigned int)f2bf(a7*iw)<<16);
                }
            }
            __syncthreads();
            *(uint4*)(hqrows + qn*HPITCH + sl*8) = nq;
            __syncthreads();
            // hqa + Q (wave-reduced)
            if (t < 128){
                float s = 0.f;
                for (int n=0;n<NQPG;n++) s += bf2f(hqrows[n*HPITCH + t]);
                hqa[t] = s;
                float qs = s*s;
                #pragma unroll
                for (int o=1;o<64;o<<=1) qs += __shfl_xor(qs, o);
                if ((t & 63) == 0) atomicAdd(&QaccL[0], qs);
            }
            __syncthreads();
            if (t == 0) Qv[l*B_+g] = QaccL[0];
            // cg2 = W1[128:256]^T @ hqa
            {
                int jj = t & 127, kc = t >> 7;
                const float* Wl = W1r + (size_t)l*32768;
                float p = 0.f;
                for (int k = kc*64; k < kc*64+64; k++)
                    p = fmaf(hqa[k], Wl[(size_t)(128+k)*128 + jj], p);
                atomicAdd(&cg2s[jj], p);
            }
            __syncthreads();
            if (t < 128) cg2a[((size_t)l*B_+g)*128 + t] = cg2s[t];
            __syncthreads();
        }
    } else {
        // ---------------- data proj -> h_g + raw nrm2 ----------------
        const int K = 64;
        int blk = bid - 2*B_;
        int wave = t >> 6, lane = t & 63;
        int quad = lane >> 4, l16 = lane & 15;
        int wrow = blk*64 + wave*16;
        floatx4 acc[8];
        #pragma unroll
        for (int t8=0;t8<8;t8++){
            #pragma unroll
            for (int r=0;r<4;r++) acc[t8][r]=0.f;
        }
        #pragma unroll
        for (int ks = 0; ks < 2; ks++){
            int koff = ks*32 + quad*8;
            const float* ap = X + (size_t)(wrow+l16)*K + koff;
            short8 a;
            #pragma unroll
            for (int j=0;j<8;j++) a[j] = (short)f2bf(ap[j]);
            #pragma unroll
            for (int t8=0;t8<8;t8++){
                short8 b = *(const short8*)(WgT_in + (size_t)(t8*16+l16)*K + koff);
                acc[t8] = __builtin_amdgcn_mfma_f32_16x16x32_bf16(a, b, acc[t8], 0,0,0);
            }
        }
        float ss[4] = {0.f,0.f,0.f,0.f};
        #pragma unroll
        for (int t8=0;t8<8;t8++){
            int col = t8*16 + l16;
            float bv = bg[col];
            #pragma unroll
            for (int r=0;r<4;r++){
                float v = acc[t8][r] + bv;
                h_g[(size_t)(wrow + quad*4 + r)*128 + col] = f2bf(v);
                ss[r] += v*v;
            }
        }
        #pragma unroll
        for (int r=0;r<4;r++){
            #pragma unroll
            for (int o=1;o<16;o<<=1) ss[r] += __shfl_xor(ss[r], o);
        }
        if (l16==0){
            #pragma unroll
            for (int r=0;r<4;r++) nrm2[wrow + quad*4 + r] = ss[r];
        }
    }
}

// ========== fused per-layer back-end: gstage (16 waves) + MLP (16 waves) ===
// phase-1 LDS: hrows 0..139264 | inv ..141312 | ssrc ..149504 |
//              offc ..151556 | nprm ..152580 (pad 152592)
// phase-2 LDS (hrows region is dead): W1s 0..34816 | W2s ..69632 |
//              h1 (256x136) ..139264 | hsum/red2 overlay inv ..140288
//              offc/nprm survive (untouched).
#define SMEM_GM 152592
#define CIDX(x) ((x) < je1 ? (x) : je1)
#define ROW(i) (*(const uint4*)(hrows + (i)*HPITCH + sl*8))
#define COMP4(U0,U1,U2,U3,I0,I1,I2,I3,JB) do { \
    float v0 = dot8q(U0, ud, Qs); \
    float v1 = dot8q(U1, ud, Qs); \
    float v2 = dot8q(U2, ud, Qs); \
    float v3 = dot8q(U3, ud, Qs); \
    red16dpp4(v0, v1, v2, v3); \
    float e0 = FEXP2(v0 * I0 * bn); \
    float e1 = FEXP2(v1 * I1 * bn); \
    float e2 = FEXP2(v2 * I2 * bn); \
    float e3 = FEXP2(v3 * I3 * bn); \
    if ((JB)+1 >= jend) e1 = 0.f; \
    if ((JB)+2 >= jend) e2 = 0.f; \
    if ((JB)+3 >= jend) e3 = 0.f; \
    ws += (e0 + e1) + (e2 + e3); \
    ax += e0 * bf2x2(U0.x); ay += e0 * bf2x2(U0.y); \
    az += e0 * bf2x2(U0.z); aw += e0 * bf2x2(U0.w); \
    ax += e1 * bf2x2(U1.x); ay += e1 * bf2x2(U1.y); \
    az += e1 * bf2x2(U1.z); aw += e1 * bf2x2(U1.w); \
    ax += e2 * bf2x2(U2.x); ay += e2 * bf2x2(U2.y); \
    az += e2 * bf2x2(U2.z); aw += e2 * bf2x2(U2.w); \
    ax += e3 * bf2x2(U3.x); ay += e3 * bf2x2(U3.y); \
    az += e3 * bf2x2(U3.z); aw += e3 * bf2x2(U3.w); \
} while(0)
__global__ __launch_bounds__(1024) void k_gm(
        const unsigned short* __restrict__ h_g,
        const float* __restrict__ nrm2g,
        const float* __restrict__ betag_p,
        const float* __restrict__ Qv_l,
        const unsigned short* __restrict__ csrc_g,
        const int* __restrict__ off_g,
        const unsigned short* __restrict__ nodeperm,
        unsigned short* __restrict__ aout,
        const unsigned short* __restrict__ W1t, const float* __restrict__ b1,
        const float* __restrict__ cg2, const unsigned short* __restrict__ W2t,
        const float* __restrict__ b2,
        unsigned short* __restrict__ hg_out, float* __restrict__ nrm2out,
        const float* __restrict__ Wp1, const float* __restrict__ bp1,
        const float* __restrict__ Wp2, const float* __restrict__ bp2,
        float* __restrict__ y){
    extern __shared__ __align__(16) char smem[];
    unsigned short* hrows = (unsigned short*)smem;
    float* inv            = (float*)(smem + 139264);
    unsigned short* ssrc  = (unsigned short*)(smem + 141312);
    int* offc             = (int*)(smem + 149504);
    unsigned short* nprm  = (unsigned short*)(smem + 151556);
    int g = blockIdx.x, t = threadIdx.x;
    int group = t >> 4, sl = t & 15;
    float beta_g = betag_p[0];
    int gbase = g*NPG;
    size_t ebase = (size_t)g*EPG;
    int wave = t>>6, lane = t&63, quad = lane>>4, l16 = lane&15;
    float Q = Qv_l[g];
    // ---- stage ----
    for (int i=t; i<8192; i+=1024){
        int row = i >> 4, col = i & 15;
        *(uint4*)(hrows + row*HPITCH + col*8) =
            *(const uint4*)(h_g + (size_t)(gbase+row)*128 + col*8);
    }
    for (int n=t; n<NPG; n+=1024){
        inv[n] = rsqrtf(nrm2g[gbase+n] + Q + 1e-24f);
        nprm[n] = nodeperm[g*NPG+n];
    }
    for (int i=t; i<EPG; i+=1024) ssrc[i] = csrc_g[ebase+i];
    for (int n=t; n<=NPG; n+=1024) offc[n] = (n<NPG) ? off_g[g*NPG+n] : EPG;
    __syncthreads();
    float Qs = Q * 0.0625f;   // folded into dot init; 16-lane sum restores +Q
    // ---- edge loop (R7-proven body) -> aout ----
    for (int idx = group; idx < NPG; idx += 64){
        int n = nprm[idx];
        int o = offc[n];
        int jend = offc[n+1];
        uint4 ov;
        if (jend > o){
            uint4 ud = *(const uint4*)(hrows + n*HPITCH + sl*8);
            float bn = beta_g * inv[n] * LOG2E_;
            float ws = 0.f;
            float2v ax; ax.x=0.f; ax.y=0.f;
            float2v ay = ax, az = ax, aw = ax;
            int je1 = jend - 1;
            int iA0 = ssrc[o];
            int iA1 = ssrc[CIDX(o+1)];
            int iA2 = ssrc[CIDX(o+2)];
            int iA3 = ssrc[CIDX(o+3)];
            uint4 uA0 = ROW(iA0);
            uint4 uA1 = ROW(iA1);
            uint4 uA2 = ROW(iA2);
            uint4 uA3 = ROW(iA3);
            float vA0 = inv[iA0], vA1 = inv[iA1], vA2 = inv[iA2], vA3 = inv[iA3];
            int iB0 = ssrc[CIDX(o+4)];
            int iB1 = ssrc[CIDX(o+5)];
            int iB2 = ssrc[CIDX(o+6)];
            int iB3 = ssrc[CIDX(o+7)];
            int j = o;
            for (;;){
                uint4 uB0 = ROW(iB0);
                uint4 uB1 = ROW(iB1);
                uint4 uB2 = ROW(iB2);
                uint4 uB3 = ROW(iB3);
                float vB0 = inv[iB0], vB1 = inv[iB1], vB2 = inv[iB2], vB3 = inv[iB3];
                iA0 = ssrc[CIDX(j+8)];
                iA1 = ssrc[CIDX(j+9)];
                iA2 = ssrc[CIDX(j+10)];
                iA3 = ssrc[CIDX(j+11)];
                COMP4(uA0,uA1,uA2,uA3, vA0,vA1,vA2,vA3, j);
                j += 4; if (j >= jend) break;
                uA0 = ROW(iA0);
                uA1 = ROW(iA1);
                uA2 = ROW(iA2);
                uA3 = ROW(iA3);
                vA0 = inv[iA0]; vA1 = inv[iA1]; vA2 = inv[iA2]; vA3 = inv[iA3];
                iB0 = ssrc[CIDX(j+8)];
                iB1 = ssrc[CIDX(j+9)];
                iB2 = ssrc[CIDX(j+10)];
                iB3 = ssrc[CIDX(j+11)];
                COMP4(uB0,uB1,uB2,uB3, vB0,vB1,vB2,vB3, j);
                j += 4; if (j >= jend) break;
            }
            float iw = __frcp_rn(ws);
            ov.x = (unsigned int)f2bf(ax.x*iw) | ((unsigned int)f2bf(ax.y*iw)<<16);
            ov.y = (unsigned int)f2bf(ay.x*iw) | ((unsigned int)f2bf(ay.y*iw)<<16);
            ov.z = (unsigned int)f2bf(az.x*iw) | ((unsigned int)f2bf(az.y*iw)<<16);
            ov.w = (unsigned int)f2bf(aw.x*iw) | ((unsigned int)f2bf(aw.y*iw)<<16);
        } else {
            ov.x=0; ov.y=0; ov.z=0; ov.w=0;
        }
        *(uint4*)(aout + (size_t)(gbase+n)*128 + sl*8) = ov;
    }
    __syncthreads();   // hrows reads + aout writes drained
    // ---- MLP phase: all 16 waves, 256 rows/pass, 2 passes ----
    unsigned short* W1s = (unsigned short*)smem;        // 128 x 136
    unsigned short* W2s = W1s + 128*136;                // 128 x 136
    unsigned short* h1  = W2s + 128*136;                // 256 x 136
    float* hsum = (float*)(smem + 139264);              // 128 f32
    float* red2 = hsum + 128;                           // 128 f32
    #pragma unroll
    for (int p=0;p<2;p++){
        int flat = p*8192 + t*8;
        int n = flat>>7, k = flat&127;
        *(uint4*)(W1s + n*136 + k) = *(const uint4*)(W1t + n*128 + k);
        *(uint4*)(W2s + n*136 + k) = *(const uint4*)(W2t + n*128 + k);
    }
    __syncthreads();
    const int last = (y != nullptr);
    const float* cg = cg2 + (size_t)g*128;   // per-graph offset
    float psum[8];
    #pragma unroll
    for (int j=0;j<8;j++) psum[j] = 0.f;
    for (int it=0; it<2; it++){
        int rowb = it*256 + wave*16;   // graph-local row base for this wave
        short8 af[4];
        #pragma unroll
        for (int ks=0;ks<4;ks++)
            af[ks] = *(const short8*)(aout + (size_t)(gbase+rowb+l16)*128 + ks*32 + quad*8);
        floatx4 acc[8];
        #pragma unroll
        for (int t8=0;t8<8;t8++){
            #pragma unroll
            for (int r=0;r<4;r++) acc[t8][r]=0.f;
        }
        #pragma unroll
        for (int ks=0;ks<4;ks++){
            int koff = ks*32 + quad*8;
            #pragma unroll
            for (int t8=0;t8<8;t8++){
                short8 b = *(const short8*)(W1s + (t8*16+l16)*136 + koff);
                acc[t8] = __builtin_amdgcn_mfma_f32_16x16x32_bf16(af[ks], b, acc[t8], 0,0,0);
            }
        }
        int lrow = wave*16;            // h1-local row base
        #pragma unroll
        for (int t8=0;t8<8;t8++){
            int col = t8*16 + l16;
            float bv = b1[col];
            float cv = cg[col];
            #pragma unroll
            for (int r=0;r<4;r++){
                int row = rowb + quad*4 + r;
                float dgv = (offc[row+1] > offc[row]) ? 1.f : 0.f;
                float v = acc[t8][r] + bv + dgv*cv;
                v = v > 0.f ? v : 0.f;
                h1[(lrow + quad*4 + r)*136 + col] = f2bf(v);
            }
        }
        __syncthreads();
        short8 hf[4];
        #pragma unroll
        for (int ks=0;ks<4;ks++)
            hf[ks] = *(const short8*)(h1 + (lrow+l16)*136 + ks*32 + quad*8);
        floatx4 acc2[8];
        #pragma unroll
        for (int t8=0;t8<8;t8++){
            #pragma unroll
            for (int r=0;r<4;r++) acc2[t8][r]=0.f;
        }
        #pragma unroll
        for (int ks=0;ks<4;ks++){
            int koff = ks*32 + quad*8;
            #pragma unroll
            for (int t8=0;t8<8;t8++){
                short8 b = *(const short8*)(W2s + (t8*16+l16)*136 + koff);
                acc2[t8] = __builtin_amdgcn_mfma_f32_16x16x32_bf16(hf[ks], b, acc2[t8], 0,0,0);
            }
        }
        float ss[4] = {0.f,0.f,0.f,0.f};
        #pragma unroll
        for (int t8=0;t8<8;t8++){
            int col = t8*16 + l16;
            float bv = b2[col];
            #pragma unroll
            for (int r=0;r<4;r++){
                float v = acc2[t8][r] + bv;
                if (last){
                    psum[t8] += v;
                } else {
                    hg_out[(size_t)(gbase + rowb + quad*4 + r)*128 + col] = f2bf(v);
                    ss[r] += v*v;
                }
            }
        }
        if (!last){
            #pragma unroll
            for (int r=0;r<4;r++){
                #pragma unroll
                for (int o=1;o<16;o<<=1) ss[r] += __shfl_xor(ss[r], o);
            }
            if (l16==0){
                #pragma unroll
                for (int r=0;r<4;r++)
                    nrm2out[gbase + rowb + quad*4 + r] = ss[r];
            }
        }
        __syncthreads();
    }
    // ---- fused predictor (last layer only) ----
    if (last){
        if (t < 128) hsum[t] = 0.f;
        __syncthreads();
        #pragma unroll
        for (int j=0;j<8;j++){
            psum[j] += __shfl_xor(psum[j], 16);
            psum[j] += __shfl_xor(psum[j], 32);
        }
        if (lane < 16){
            #pragma unroll
            for (int j=0;j<8;j++) atomicAdd(&hsum[j*16 + lane], psum[j]);
        }
        __syncthreads();
        if (t < 128){
            float acc = bp1[t];
            for (int k=0;k<128;k++) acc += hsum[k]*Wp1[k*128+t];
            acc = fmaxf(acc, 0.f);
            red2[t] = acc * Wp2[t];
        }
        __syncthreads();
        for (int s2=64; s2>0; s2>>=1){
            if (t<s2) red2[t]+=red2[t+s2];
            __syncthreads();
        }
        if (t==0) y[g] = red2[0] + bp2[0];
    }
}

extern "C" void kernel_launch(void* const* d_in, const int* in_sizes, int n_in,
                              void* d_out, int out_size, void* d_ws, size_t ws_size,
                              hipStream_t stream) {
    const float* X    = (const float*)d_in[0];
    const float* X_q  = (const float*)d_in[1];
    const int* g_src = (const int*)d_in[2];
    const int* g_dst = (const int*)d_in[3];
    const int* q_src = (const int*)d_in[5];
    const int* q_dst = (const int*)d_in[6];
    const float* Wg   = (const float*)d_in[8];
    const float* bg   = (const float*)d_in[9];
    const float* Wq   = (const float*)d_in[10];
    const float* bq   = (const float*)d_in[11];
    const float* betas_g = (const float*)d_in[12];
    const float* betas_q = (const float*)d_in[13];
    const float* W1r  = (const float*)d_in[14];
    const float* b1r  = (const float*)d_in[15];
    const float* W2r  = (const float*)d_in[16];
    const float* b2r  = (const float*)d_in[17];
    const float* Wp1  = (const float*)d_in[18];
    const float* bp1  = (const float*)d_in[19];
    const float* Wp2  = (const float*)d_in[20];
    const float* bp2  = (const float*)d_in[21];

    uint8_t* w = (uint8_t*)d_ws;
    unsigned short* h_g  = (unsigned short*)w;    w += (size_t)NG*128*2;
    unsigned short* aout = (unsigned short*)w;    w += (size_t)NG*128*2;
    float* nrm2  = (float*)w;                     w += (size_t)NG*4;
    float* degf  = (float*)w;                     w += (size_t)NG*4;
    float* Qv    = (float*)w;                     w += (size_t)L_*B_*4;
    float* cg2a  = (float*)w;                     w += (size_t)L_*B_*128*4;
    unsigned short* WgT   = (unsigned short*)w;   w += 8192*2;
    unsigned short* W1aT  = (unsigned short*)w;   w += 2*16384*2;
    unsigned short* W2rT  = (unsigned short*)w;   w += 2*16384*2;
    unsigned short* csrc_g = (unsigned short*)w;  w += (size_t)B_*EPG*2;
    unsigned short* nodeperm = (unsigned short*)w; w += (size_t)B_*NPG*2;
    int* off_g = (int*)w;                         w += (size_t)B_*NPG*4;

    static bool attr_done = false;
    if (!attr_done){
        hipFuncSetAttribute((const void*)k_gm,
                            hipFuncAttributeMaxDynamicSharedMemorySize, SMEM_GM);
        attr_done = true;
    }

    // front-end: csrt (256) | queryall (256) | proj (2048) in one launch
    k_mega<<<2*B_ + NG/64, 256, SMEM_MEGA, stream>>>(
        g_src, g_dst, Wg, W1r, W2r, WgT, W1aT, W2rT,
        csrc_g, off_g, degf, nodeperm,
        X_q, Wq, bq, q_src, q_dst, betas_q, Qv, cg2a,
        X, WgT, bg, h_g, nrm2);
    // back-end: per-layer fused gstage+MLP (one block per graph)
    for (int l=0;l<L_;l++){
        k_gm<<<B_, 1024, SMEM_GM, stream>>>(
            h_g, nrm2, betas_g + l, Qv + l*B_,
            csrc_g, off_g, nodeperm, aout,
            W1aT + l*16384, b1r + l*128, cg2a + (size_t)l*B_*128,
            W2rT + l*16384, b2r + l*128,
            h_g, (l==0) ? nrm2 : nullptr,
            Wp1, bp1, Wp2, bp2,
            (l==L_-1) ? (float*)d_out : nullptr);
    }
}